// Round 4
// baseline (292.713 us; speedup 1.0000x reference)
//
#include <hip/hip_runtime.h>

#define B_TOTAL 32768
#define NF 200
#define D_IN 5
#define NH 15
#define NOUT 30

typedef _Float16 half8 __attribute__((ext_vector_type(8)));
typedef _Float16 half4_t __attribute__((ext_vector_type(4)));
typedef float f32x4 __attribute__((ext_vector_type(4)));
typedef float f32x2 __attribute__((ext_vector_type(2)));

// ws layout: Bc fp16 [f 200][half 2][n 16][k8]  (= 256 halfs/f, 102400 B)
//            w3T fp32 [part 10][w 4][n 16][slot 12] (7680 floats) at +102400 B
// Bc k8 per (f, o=half*16+n): {Wc[0..4][o], bc[o], 0, 0}; o>=30 rows written as
// zero by precompute. w3T slots 10,11 per group are never read.
#define WS_BC_BYTES 102400

#define GPF 8   // features per precompute block; 200/8 = 25 blocks

// LDS-staged precompute: coalesced float4 loads of all per-f weights, then each
// of the 256 threads computes one (f, o) folded column from LDS.
__global__ __launch_bounds__(256) void precompute_kernel(
    const float* __restrict__ W1, const float* __restrict__ b1,
    const float* __restrict__ W2, const float* __restrict__ b2,
    const float* __restrict__ W3, _Float16* __restrict__ Bc,
    float* __restrict__ w3T)
{
    __shared__ __align__(16) float sW1[GPF * 75];    // [fi][i*15+h]
    __shared__ __align__(16) float sW2[GPF * 450];   // [fi][h*30+o]
    __shared__ __align__(16) float sb1[GPF * 15];
    __shared__ __align__(16) float sb2[GPF * 30];
    __shared__ __align__(16) float sW3[GPF * 30];

    const int tid = threadIdx.x;
    const int f0  = blockIdx.x * GPF;

    // stage weights: every block slice is 16B-aligned (f0 multiple of 8)
    {
        const f32x4* g1 = (const f32x4*)(W1 + (size_t)f0 * 75);   // 150 f4
        if (tid < 150) ((f32x4*)sW1)[tid] = g1[tid];
        const f32x4* g2 = (const f32x4*)(W2 + (size_t)f0 * 450);  // 900 f4
        for (int j = tid; j < 900; j += 256) ((f32x4*)sW2)[j] = g2[j];
        if (tid < 30)
            ((f32x4*)sb1)[tid] = ((const f32x4*)(b1 + (size_t)f0 * 15))[tid];
        if (tid >= 32 && tid < 92)
            ((f32x4*)sb2)[tid - 32] = ((const f32x4*)(b2 + (size_t)f0 * 30))[tid - 32];
        if (tid >= 96 && tid < 156)
            ((f32x4*)sW3)[tid - 96] = ((const f32x4*)(W3 + (size_t)f0 * 30))[tid - 96];
    }
    __syncthreads();

    const int fi = tid >> 5;       // local f
    const int r  = tid & 31;       // Bc row within f
    const int hf = r >> 4;
    const int n  = r & 15;
    const int o  = hf * 16 + n;
    const int f  = f0 + fi;

    half8 row = {};                // o >= 30 rows stay all-zero
    if (o < NOUT) {
        float bcv = sb2[fi * 30 + o];
        float wc0 = 0.f, wc1 = 0.f, wc2 = 0.f, wc3 = 0.f, wc4 = 0.f;
        #pragma unroll
        for (int h = 0; h < NH; ++h) {
            const float w2v = sW2[fi * 450 + h * 30 + o];
            bcv = fmaf(sb1[fi * 15 + h], w2v, bcv);
            wc0 = fmaf(sW1[fi * 75 +  0 + h], w2v, wc0);
            wc1 = fmaf(sW1[fi * 75 + 15 + h], w2v, wc1);
            wc2 = fmaf(sW1[fi * 75 + 30 + h], w2v, wc2);
            wc3 = fmaf(sW1[fi * 75 + 45 + h], w2v, wc3);
            wc4 = fmaf(sW1[fi * 75 + 60 + h], w2v, wc4);
        }
        row[0] = (_Float16)wc0; row[1] = (_Float16)wc1; row[2] = (_Float16)wc2;
        row[3] = (_Float16)wc3; row[4] = (_Float16)wc4;
        row[5] = (_Float16)bcv; // pairs with the 1.0 bias slot in A
        row[6] = (_Float16)0.f; row[7] = (_Float16)0.f;

        const int p = f / 20, fl = f % 20, Kg = fl / 4, w = fl % 4;
        w3T[((size_t)(p * 4 + w) * 16 + n) * 12 + (Kg * 2 + hf)] = sW3[fi * 30 + o];
    }
    *(half8*)(Bc + (size_t)f * 256 + r * 8) = row;   // coalesced b128 store
}

// ---------------- Main kernel ----------------
// Grid 1024 blocks x 256 thr (4 waves); block owns 32 b-rows, loops all 10
// f-parts with acc persistent in VGPRs (no atomics, no out-zeroing, epilogue
// once). Register prefetch (T14): part p+1's y/Bc/w3 global loads issue right
// after part p's stage-barrier and complete under p's MFMA+VALU compute.
// MFMA mfma_f32_16x16x16_f16, quads 0,1 real k8, quads 2,3 zero-B (A mirrors
// q&1). Bias via the 1.0 A-column. Epilogue: LDS-transpose reduction over the
// 16 n-lanes + cross-wave combine, plain store of out (+b3).
#define FPART 20
#define NPARTS 10
#define BTILE 32

__global__ __launch_bounds__(256, 4) void mlp_kernel(
    const float* __restrict__ y, const _Float16* __restrict__ Bc,
    const float* __restrict__ w3T, const float* __restrict__ b3,
    float* __restrict__ out)
{
    __shared__ __align__(16) _Float16 sy[BTILE * 168]; // [b][fl 20 x8 + pad8]
    __shared__ __align__(16) _Float16 sB[20 * 256];    // part's Bc, linear
    __shared__ __align__(16) float    sw3[768];        // part's w3T
    __shared__ __align__(16) _Float16 szero[8];

    const int tid = threadIdx.x;
    const int b0  = blockIdx.x * BTILE;

    if (tid < 8) szero[tid] = (_Float16)0.f;

    // y staging task map: 640 tasks (b 32 x fl 20) = tid, tid+256, tid+512(<128)
    const int bt0 = tid / 20,             flt0 = tid - bt0 * 20;
    const int id1 = tid + 256;  const int bt1 = id1 / 20, flt1 = id1 - bt1 * 20;
    const int id2 = tid + 512;  const int bt2 = id2 / 20, flt2 = id2 - bt2 * 20;
    const bool has2 = (tid < 128);
    const bool hasw = (tid < 192);

    // prefetch registers for one part
    float vy0[5], vy1[5], vy2[5];
    f32x4 vB0, vB1, vB2, vw;

    const float* ybase = y + (size_t)b0 * (NF * D_IN);

    // ---- prologue: prefetch part 0 ----
    {
        const int f0 = 0;
        __builtin_memcpy(vy0, ybase + (size_t)bt0 * (NF * D_IN) + (f0 + flt0) * 5, 20);
        __builtin_memcpy(vy1, ybase + (size_t)bt1 * (NF * D_IN) + (f0 + flt1) * 5, 20);
        if (has2)
            __builtin_memcpy(vy2, ybase + (size_t)bt2 * (NF * D_IN) + (f0 + flt2) * 5, 20);
        const f32x4* g = (const f32x4*)(Bc + (size_t)f0 * 256);
        vB0 = g[tid]; vB1 = g[tid + 256];
        if (has2) vB2 = g[tid + 512];
        if (hasw) vw = ((const f32x4*)w3T)[tid];
    }

    const int lane = tid & 63;
    const int w    = tid >> 6;       // wave id == f_in_group
    const int n    = lane & 15;      // A row m / B col n / C col
    const int q    = lane >> 4;      // quad == k-block

    float acc[2][4];
    #pragma unroll
    for (int Mt = 0; Mt < 2; ++Mt)
        #pragma unroll
        for (int g = 0; g < 4; ++g) acc[Mt][g] = 0.f;
    const f32x4 z4 = {0.f, 0.f, 0.f, 0.f};

    #pragma unroll 1
    for (int p = 0; p < NPARTS; ++p) {
        __syncthreads();             // previous part's compute done; LDS free
        // ---- write staged registers to LDS ----
        {
            half8 h;
            h[0]=(_Float16)vy0[0]; h[1]=(_Float16)vy0[1]; h[2]=(_Float16)vy0[2];
            h[3]=(_Float16)vy0[3]; h[4]=(_Float16)vy0[4];
            h[5]=(_Float16)1.0f;   h[6]=(_Float16)0.f;    h[7]=(_Float16)0.f;
            *(half8*)&sy[bt0 * 168 + flt0 * 8] = h;
            h[0]=(_Float16)vy1[0]; h[1]=(_Float16)vy1[1]; h[2]=(_Float16)vy1[2];
            h[3]=(_Float16)vy1[3]; h[4]=(_Float16)vy1[4];
            h[5]=(_Float16)1.0f;
            *(half8*)&sy[bt1 * 168 + flt1 * 8] = h;
            if (has2) {
                h[0]=(_Float16)vy2[0]; h[1]=(_Float16)vy2[1]; h[2]=(_Float16)vy2[2];
                h[3]=(_Float16)vy2[3]; h[4]=(_Float16)vy2[4];
                h[5]=(_Float16)1.0f;
                *(half8*)&sy[bt2 * 168 + flt2 * 8] = h;
            }
            f32x4* s = (f32x4*)sB;
            s[tid] = vB0; s[tid + 256] = vB1;
            if (has2) s[tid + 512] = vB2;
            if (hasw) ((f32x4*)sw3)[tid] = vw;
        }
        __syncthreads();
        // ---- issue prefetch for part p+1 (lands under this part's compute) ----
        if (p + 1 < NPARTS) {
            const int f0 = (p + 1) * FPART;
            __builtin_memcpy(vy0, ybase + (size_t)bt0 * (NF * D_IN) + (f0 + flt0) * 5, 20);
            __builtin_memcpy(vy1, ybase + (size_t)bt1 * (NF * D_IN) + (f0 + flt1) * 5, 20);
            if (has2)
                __builtin_memcpy(vy2, ybase + (size_t)bt2 * (NF * D_IN) + (f0 + flt2) * 5, 20);
            const f32x4* g = (const f32x4*)(Bc + (size_t)f0 * 256);
            vB0 = g[tid]; vB1 = g[tid + 256];
            if (has2) vB2 = g[tid + 512];
            if (hasw) vw = ((const f32x4*)w3T)[(size_t)(p + 1) * 192 + tid];
        }
        // ---- compute this part ----
        #pragma unroll
        for (int Kg = 0; Kg < 5; ++Kg) {
            const int fl = Kg * 4 + w;   // this wave's f_local
            const half4_t A0 = *(const half4_t*)&sy[n        * 168 + fl * 8 + (q & 1) * 4];
            const half4_t A1 = *(const half4_t*)&sy[(16 + n) * 168 + fl * 8 + (q & 1) * 4];
            const _Float16* bq0 = (q < 2) ? &sB[fl * 256 + n * 8 + (q & 1) * 4]        : szero;
            const _Float16* bq1 = (q < 2) ? &sB[fl * 256 + (16 + n) * 8 + (q & 1) * 4] : szero;
            const half4_t Bf0 = *(const half4_t*)bq0;
            const half4_t Bf1 = *(const half4_t*)bq1;
            const f32x2 w3p = *(const f32x2*)&sw3[(w * 16 + n) * 12 + Kg * 2];

            f32x4 c;
            c = __builtin_amdgcn_mfma_f32_16x16x16f16(A0, Bf0, z4, 0, 0, 0);
            #pragma unroll
            for (int g = 0; g < 4; ++g) acc[0][g] += fmaxf(c[g], 0.f) * w3p[0];
            c = __builtin_amdgcn_mfma_f32_16x16x16f16(A0, Bf1, z4, 0, 0, 0);
            #pragma unroll
            for (int g = 0; g < 4; ++g) acc[0][g] += fmaxf(c[g], 0.f) * w3p[1];
            c = __builtin_amdgcn_mfma_f32_16x16x16f16(A1, Bf0, z4, 0, 0, 0);
            #pragma unroll
            for (int g = 0; g < 4; ++g) acc[1][g] += fmaxf(c[g], 0.f) * w3p[0];
            c = __builtin_amdgcn_mfma_f32_16x16x16f16(A1, Bf1, z4, 0, 0, 0);
            #pragma unroll
            for (int g = 0; g < 4; ++g) acc[1][g] += fmaxf(c[g], 0.f) * w3p[1];
        }
    }

    // ---- epilogue (once): LDS-transpose reduction over the 16 n-lanes ----
    __syncthreads();                  // all waves done reading sy/sB
    float* sacc = (float*)sy;         // [w][row 32][stride 20 dw] = 10240 B
    {
        float* base = sacc + w * (32 * 20);
        #pragma unroll
        for (int Mt = 0; Mt < 2; ++Mt)
            #pragma unroll
            for (int g = 0; g < 4; ++g)
                base[(Mt * 16 + q * 4 + g) * 20 + n] = acc[Mt][g];  // 2-way max
    }
    float v = 0.f;
    if (lane < 32) {                  // per-wave row sums (in-wave DS ordering)
        const float* srow = sacc + w * (32 * 20) + lane * 20;
        const f32x4 r0 = *(const f32x4*)(srow);
        const f32x4 r1 = *(const f32x4*)(srow + 4);
        const f32x4 r2 = *(const f32x4*)(srow + 8);
        const f32x4 r3 = *(const f32x4*)(srow + 12);
        v = ((r0[0] + r0[1]) + (r0[2] + r0[3]))
          + ((r1[0] + r1[1]) + (r1[2] + r1[3]))
          + ((r2[0] + r2[1]) + (r2[2] + r2[3]))
          + ((r3[0] + r3[1]) + (r3[2] + r3[3]));
    }
    float* sp = (float*)sB;           // [w][32] scratch
    if (lane < 32) sp[w * 32 + lane] = v;
    __syncthreads();
    if (tid < 32) {
        const float s = (sp[tid] + sp[32 + tid]) + (sp[64 + tid] + sp[96 + tid]) + b3[0];
        out[b0 + tid] = s;            // plain coalesced store, written once
    }
}

extern "C" void kernel_launch(void* const* d_in, const int* in_sizes, int n_in,
                              void* d_out, int out_size, void* d_ws, size_t ws_size,
                              hipStream_t stream) {
    const float* y  = (const float*)d_in[0];
    const float* W1 = (const float*)d_in[1];
    const float* b1 = (const float*)d_in[2];
    const float* W2 = (const float*)d_in[3];
    const float* b2 = (const float*)d_in[4];
    const float* W3 = (const float*)d_in[5];
    const float* b3 = (const float*)d_in[6];
    float* out = (float*)d_out;

    _Float16* Bc  = (_Float16*)d_ws;
    float*    w3T = (float*)((char*)d_ws + WS_BC_BYTES);

    // no memsets: mlp writes every out element exactly once (plain store);
    // precompute writes every Bc byte (pad rows included).
    precompute_kernel<<<NF / GPF, 256, 0, stream>>>(W1, b1, W2, b2, W3, Bc, w3T);
    mlp_kernel<<<B_TOTAL / BTILE, 256, 0, stream>>>(y, Bc, w3T, b3, out);
}